// Round 13
// baseline (5362.234 us; speedup 1.0000x reference)
//
#include <hip/hip_runtime.h>
#include <math.h>

#define Tt 128
#define NT 512
#define EPSF 1e-8f
#define WC_OFF 65536   // u32 offset of C-matmul weights in wsb

typedef _Float16 f16x2 __attribute__((ext_vector_type(2)));

__device__ __forceinline__ float fsigmoid(float v) { return 1.f / (1.f + expf(-v)); }
__device__ __forceinline__ float fsoftplus(float v) { return (v > 20.f) ? v : log1pf(expf(v)); }
__device__ __forceinline__ float ftanh(float v) { float e = expf(2.f * v); return 1.f - 2.f / (e + 1.f); }

__device__ __forceinline__ float dot2(f16x2 a, f16x2 b, float c) {
#if __has_builtin(__builtin_amdgcn_fdot2)
  return __builtin_amdgcn_fdot2(a, b, c, false);
#else
  return c + (float)a.x * (float)b.x + (float)a.y * (float)b.y;
#endif
}
__device__ __forceinline__ f16x2 pack2(float a, float b) {
  f16x2 p; p.x = (_Float16)a; p.y = (_Float16)b; return p;
}
__device__ __forceinline__ f16x2 bc16(unsigned int v) { return __builtin_bit_cast(f16x2, v); }

// ---- DPP reduction primitives ----
template <int C> __device__ __forceinline__ float dppadd(float v) {
  int s = __builtin_amdgcn_update_dpp(0, __builtin_bit_cast(int, v), C, 0xf, 0xf, true);
  return v + __builtin_bit_cast(float, s);
}
template <int C> __device__ __forceinline__ float dppmax(float v) {
  int iv = __builtin_bit_cast(int, v);
  int s = __builtin_amdgcn_update_dpp(iv, iv, C, 0xf, 0xf, false);
  return fmaxf(v, __builtin_bit_cast(float, s));
}
__device__ __forceinline__ float qsum16(float v) {
  v = dppadd<0x111>(v); v = dppadd<0x112>(v); v = dppadd<0x114>(v); v = dppadd<0x118>(v);
  return v;
}
__device__ __forceinline__ float halfsum(float v) {  // lane31/63 hold 32-lane sums
  v = qsum16(v); v = dppadd<0x142>(v);
  return v;
}
__device__ __forceinline__ float allsum(float v) {
  v = halfsum(v); v = dppadd<0x143>(v);
  return __builtin_bit_cast(float, __builtin_amdgcn_readlane(__builtin_bit_cast(int, v), 63));
}
__device__ __forceinline__ float allmax(float v) {
  v = dppmax<0x111>(v); v = dppmax<0x112>(v); v = dppmax<0x114>(v);
  v = dppmax<0x118>(v); v = dppmax<0x142>(v); v = dppmax<0x143>(v);
  return __builtin_bit_cast(float, __builtin_amdgcn_readlane(__builtin_bit_cast(int, v), 63));
}

// ===== prep: pack weights f32 -> f16x2 (same layout as round 12) =====
__global__ __launch_bounds__(256, 1) void ntm_prep(
    const float* __restrict__ We, const float* __restrict__ Wa,
    const float* __restrict__ Wk, const float* __restrict__ Wx,
    const float* __restrict__ Wrd, unsigned int* __restrict__ wsb)
{
  const int i = blockIdx.x * 256 + threadIdx.x;   // grid 384*256 = 98304
  if (i < 65536) {
    const int e = i & 3;
    const int cg = (i >> 2) & 63;
    const int q = (i >> 8) & 7;
    const int js = (i >> 11) & 3;
    const int c = (i >> 13) & 7;
    const int jj = q * 4 + e;
    const int row0 = js * 64 + 2 * jj;
    const int col = (c & 1) * 64 + cg;
    const int mat = c >> 1;
    const float* base = (mat == 0) ? We : (mat == 1) ? Wa : (mat == 2) ? Wk : (Wk + 256 * 128);
    wsb[i] = __builtin_bit_cast(unsigned int, pack2(base[row0 * 128 + col], base[(row0 + 1) * 128 + col]));
  } else {
    const int j = i - WC_OFF;
    const int e = j & 3;
    const int cg = (j >> 2) & 63;
    const int q = (j >> 8) & 7;
    const int js = (j >> 11) & 3;
    const int c2 = (j >> 13) & 3;
    const int jj = q * 4 + e;
    const int row0 = js * 64 + 2 * jj;
    const int col = c2 * 64 + cg;
    float v0, v1;
    if (row0 < 128) { v0 = Wx[row0 * 256 + col]; v1 = Wx[(row0 + 1) * 256 + col]; }
    else            { v0 = Wrd[(row0 - 128) * 256 + col]; v1 = Wrd[(row0 - 127) * 256 + col]; }
    wsb[i] = __builtin_bit_cast(unsigned int, pack2(v0, v1));
  }
}

__global__ __launch_bounds__(NT, 1) void ntm_kernel(
    const float* __restrict__ x, const float* __restrict__ mem0,
    const float* __restrict__ wr0, const float* __restrict__ ww0,
    const float* __restrict__ h0, const float* __restrict__ bh,
    const float* __restrict__ bk,
    const float* __restrict__ Wb, const float* __restrict__ bb,
    const float* __restrict__ Wg, const float* __restrict__ bg,
    const float* __restrict__ Ws, const float* __restrict__ bs,
    const float* __restrict__ Wgam, const float* __restrict__ bgam,
    const float* __restrict__ be, const float* __restrict__ ba,
    const uint4* __restrict__ wsb4,
    float* __restrict__ out)
{
  const int t = threadIdx.x;
  const int batch = t >> 8;        // waves 0-3: batch A, 4-7: batch B
  const int u = t & 255;           // within-batch thread id
  const int lane = t & 63;
  const int wave4 = (t >> 6) & 3;  // wave within batch
  const int cg = u & 63;
  const int js = u >> 6;           // inner-dim slice (4 slices of 64)
  const int c4 = u & 31;
  const int rs = u >> 5;           // row slice (8)
  const int gb = blockIdx.x * 2 + batch;

  // 160944 B total <= 160 KiB
  __shared__ __align__(16) float mem[2][16384];
  __shared__ __align__(16) float part[2][2048];     // [1024..1279] doubles as dotv
  __shared__ __align__(16) float h_l[2][256];
  __shared__ unsigned int xf16[2][64];
  __shared__ unsigned int rf16[2][64];
  __shared__ __align__(16) float er[2][128];
  __shared__ __align__(16) float ad[2][128];
  __shared__ __align__(16) float kbuf[2][256];
  __shared__ float wr_s[2][128], ww_s[2][128];
  __shared__ float normsq[2][128];
  __shared__ float scal[2][12];
  __shared__ float red2[2][4];
  __shared__ float bias_big[512];                   // [be | ba | bk0 | bk1]
  __shared__ float bh_l[256];
  __shared__ float bias_sm[12];

  // ===== state / bias init (both batches write identical shared values — benign) =====
  for (int i = u; i < 4096; i += 256)
    reinterpret_cast<float4*>(mem[batch])[i] = reinterpret_cast<const float4*>(mem0)[i];
  if (u < 128) { wr_s[batch][u] = wr0[gb * 128 + u]; ww_s[batch][u] = ww0[gb * 128 + u]; }
  h_l[batch][u] = h0[gb * 256 + u];
  bh_l[u] = bh[u];
  bias_big[u] = (u < 128) ? be[u] : ba[u - 128];
  bias_big[u + 256] = bk[u];
  if (u < 12) {
    const int head = u / 6, kind = u % 6;
    bias_sm[u] = (kind == 0) ? bb[head] : (kind == 1) ? bg[head]
               : (kind == 2) ? bgam[head] : bs[head * 3 + (kind - 3)];
  }
  __syncthreads();

  // ---- big4 matmul partials from h_l; weights streamed from L2
  auto phase_big4 = [&]() {
    f16x2 hh[32];
    #pragma unroll
    for (int j = 0; j < 32; ++j) {
      const float2 h2 = *reinterpret_cast<const float2*>(&h_l[batch][js * 64 + 2 * j]);
      hh[j] = pack2(h2.x, h2.y);
    }
    float acc[8];
    #pragma unroll
    for (int c = 0; c < 8; ++c) acc[c] = 0.f;
    #pragma unroll
    for (int c = 0; c < 8; ++c) {
      const uint4* p = wsb4 + ((c * 4 + js) * 8) * 64 + cg;
      uint4 w[8];
      #pragma unroll
      for (int q = 0; q < 8; ++q) w[q] = p[q * 64];
      #pragma unroll
      for (int q = 0; q < 8; ++q) {
        acc[c] = dot2(hh[q * 4 + 0], bc16(w[q].x), acc[c]);
        acc[c] = dot2(hh[q * 4 + 1], bc16(w[q].y), acc[c]);
        acc[c] = dot2(hh[q * 4 + 2], bc16(w[q].z), acc[c]);
        acc[c] = dot2(hh[q * 4 + 3], bc16(w[q].w), acc[c]);
      }
    }
    #pragma unroll
    for (int c = 0; c < 8; ++c) part[batch][js * 512 + c * 64 + cg] = acc[c];
  };

  // ---- reduce big4 -> er/ad/kbuf + k^2 (DPP); 12 small dots from global weights
  auto phase_reduce = [&]() {
    {
      float v0 = bias_big[u];
      float v1 = bias_big[u + 256];
      #pragma unroll
      for (int s = 0; s < 4; ++s) { v0 += part[batch][s * 512 + u]; v1 += part[batch][s * 512 + u + 256]; }
      if (u < 128) er[batch][u] = fsigmoid(v0);
      else         ad[batch][u - 128] = ftanh(v0);
      float kv = ftanh(v1);
      kbuf[batch][u] = kv;
      float ks = kv * kv;
      ks = halfsum(ks); ks = dppadd<0x143>(ks);
      if (lane == 63) red2[batch][wave4] = ks;
    }
    if (u < 192) {
      const int d = u >> 4, l4 = u & 15;
      const int head = d / 6, kind = d % 6;
      const float* wp; int str;
      if (kind == 0)      { wp = Wb + head * 256;              str = 1; }
      else if (kind == 1) { wp = Wg + head * 256;              str = 1; }
      else if (kind == 2) { wp = Wgam + head * 256;            str = 1; }
      else                { wp = Ws + head * 768 + (kind - 3); str = 3; }
      float s = 0.f;
      #pragma unroll
      for (int q = 0; q < 16; ++q) { const int j = l4 + 16 * q; s += h_l[batch][j] * wp[j * str]; }
      s = qsum16(s);
      if ((lane & 15) == 15) scal[batch][d] = s + bias_sm[d];
    }
  };

  // prologue: er/ad for step 0 from h0
  phase_big4();
  __syncthreads();
  phase_reduce();
  __syncthreads();

  for (int step = 0; step < Tt; ++step) {
    float* dotv = part[batch] + 1024;   // aliased: written P7, read P8, dead by next P5

    // ---- P1: x load+pack; mem erase/add; per-row normsq; r partials
    if (u < 64) {
      const float2 xv = reinterpret_cast<const float2*>(x + ((size_t)gb * Tt + step) * 128)[u];
      xf16[batch][u] = __builtin_bit_cast(unsigned int, pack2(xv.x, xv.y));
    }
    {
      const float4 e4 = *reinterpret_cast<const float4*>(&er[batch][c4 * 4]);
      const float4 a4 = *reinterpret_cast<const float4*>(&ad[batch][c4 * 4]);
      float rx = 0.f, ry = 0.f, rz = 0.f, rw = 0.f;
      #pragma unroll
      for (int k = 0; k < 16; ++k) {
        const int n = rs + 8 * k;
        const float wwn = ww_s[batch][n], wrn = wr_s[batch][n];
        float4 v = *reinterpret_cast<const float4*>(&mem[batch][n * 128 + c4 * 4]);
        v.x = v.x * (1.f - wwn * e4.x) + wwn * a4.x;
        v.y = v.y * (1.f - wwn * e4.y) + wwn * a4.y;
        v.z = v.z * (1.f - wwn * e4.z) + wwn * a4.z;
        v.w = v.w * (1.f - wwn * e4.w) + wwn * a4.w;
        *reinterpret_cast<float4*>(&mem[batch][n * 128 + c4 * 4]) = v;
        float nsq = v.x * v.x + v.y * v.y + v.z * v.z + v.w * v.w;
        nsq = halfsum(nsq);
        if ((lane & 31) == 31) normsq[batch][n] = nsq;
        rx += wrn * v.x; ry += wrn * v.y; rz += wrn * v.z; rw += wrn * v.w;
      }
      *reinterpret_cast<float4*>(&part[batch][rs * 128 + c4 * 4]) = make_float4(rx, ry, rz, rw);
    }
    __syncthreads();  // b1

    // ---- P2: reduce r partials; pack f16x2
    if (u < 128) {
      float r = 0.f;
      #pragma unroll
      for (int s = 0; s < 8; ++s) r += part[batch][s * 128 + u];
      const float ro = __shfl_xor(r, 1);
      if (!(u & 1)) rf16[batch][u >> 1] = __builtin_bit_cast(unsigned int, pack2(r, ro));
    }
    __syncthreads();  // b2

    // ---- P3: C-matmul partials from [x|r]; weights streamed from L2
    {
      const unsigned int* src16 = (js < 2) ? (xf16[batch] + js * 32) : (rf16[batch] + (js - 2) * 32);
      f16x2 xx[32];
      #pragma unroll
      for (int j = 0; j < 32; ++j) xx[j] = bc16(src16[j]);
      float acc[4];
      #pragma unroll
      for (int c = 0; c < 4; ++c) acc[c] = 0.f;
      #pragma unroll
      for (int c = 0; c < 4; ++c) {
        const uint4* p = wsb4 + (WC_OFF / 4) + ((c * 4 + js) * 8) * 64 + cg;
        uint4 w[8];
        #pragma unroll
        for (int q = 0; q < 8; ++q) w[q] = p[q * 64];
        #pragma unroll
        for (int q = 0; q < 8; ++q) {
          acc[c] = dot2(xx[q * 4 + 0], bc16(w[q].x), acc[c]);
          acc[c] = dot2(xx[q * 4 + 1], bc16(w[q].y), acc[c]);
          acc[c] = dot2(xx[q * 4 + 2], bc16(w[q].z), acc[c]);
          acc[c] = dot2(xx[q * 4 + 3], bc16(w[q].w), acc[c]);
        }
      }
      #pragma unroll
      for (int c = 0; c < 4; ++c) part[batch][js * 256 + c * 64 + cg] = acc[c];
    }
    __syncthreads();  // b3

    // ---- P4: h = tanh(.); write out
    {
      float v = bh_l[u];
      #pragma unroll
      for (int s = 0; s < 4; ++s) v += part[batch][s * 256 + u];
      v = ftanh(v);
      h_l[batch][u] = v;
      out[((size_t)gb * Tt + step) * 256 + u] = v;
    }
    __syncthreads();  // b4

    // ---- P5/P6: big4 + reduce from new h
    phase_big4();
    __syncthreads();  // b5
    phase_reduce();
    __syncthreads();  // b6

    // ---- P7: content dots (32 rows/thread, chunks of 8)
    {
      const int head = u >> 7;
      const int v7 = u & 127;
      const int cc = v7 & 31, ns = v7 >> 5;
      const float4 k4 = *reinterpret_cast<const float4*>(&kbuf[batch][head * 128 + cc * 4]);
      #pragma unroll
      for (int ch = 0; ch < 4; ++ch) {
        float dsum[8];
        #pragma unroll
        for (int ii = 0; ii < 8; ++ii) {
          const int n = ns * 32 + ch * 8 + ii;
          const float4 m4 = *reinterpret_cast<const float4*>(&mem[batch][n * 128 + cc * 4]);
          dsum[ii] = k4.x * m4.x + k4.y * m4.y + k4.z * m4.z + k4.w * m4.w;
        }
        #pragma unroll
        for (int ii = 0; ii < 8; ++ii) dsum[ii] = halfsum(dsum[ii]);
        if ((lane & 31) == 31) {
          #pragma unroll
          for (int ii = 0; ii < 8; ++ii) dotv[head * 128 + ns * 32 + ch * 8 + ii] = dsum[ii];
        }
      }
    }
    __syncthreads();  // b7

    // ---- P8: addressing tail; waves {0,1} of each batch = heads {0,1}
    if (wave4 < 2) {
      const int head = wave4;
      const int h6 = head * 6;
      const float beta  = fsoftplus(scal[batch][h6]);
      const float g     = fsigmoid(scal[batch][h6 + 1]);
      const float gamma = 1.f + fsoftplus(scal[batch][h6 + 2]);
      float e0 = scal[batch][h6 + 3], e1 = scal[batch][h6 + 4], e2 = scal[batch][h6 + 5];
      const float mx3 = fmaxf(e0, fmaxf(e1, e2));
      float x0 = expf(e0 - mx3), x1 = expf(e1 - mx3), x2 = expf(e2 - mx3);
      const float si = 1.f / (x0 + x1 + x2);
      const float s0 = x0 * si, s1 = x1 * si, s2 = x2 * si;
      const float knorm = sqrtf(red2[batch][2 * head] + red2[batch][2 * head + 1]);
      float* wprev = head ? ww_s[batch] : wr_s[batch];
      const int n0 = 2 * lane, n1 = 2 * lane + 1;
      float l0 = beta * dotv[head * 128 + n0] / (knorm * sqrtf(normsq[batch][n0]) + EPSF);
      float l1 = beta * dotv[head * 128 + n1] / (knorm * sqrtf(normsq[batch][n1]) + EPSF);
      const float mx = allmax(fmaxf(l0, l1));
      float q0 = expf(l0 - mx), q1 = expf(l1 - mx);
      const float inv = 1.f / allsum(q0 + q1);
      const float wg0 = g * q0 * inv + (1.f - g) * wprev[n0];
      const float wg1 = g * q1 * inv + (1.f - g) * wprev[n1];
      const float wgl = __shfl(wg1, (lane + 63) & 63);
      const float wgr = __shfl(wg0, (lane + 1) & 63);
      const float sh0 = s0 * wgl + s1 * wg0 + s2 * wg1;
      const float sh1 = s0 * wg0 + s1 * wg1 + s2 * wgr;
      const float wp0 = exp2f(gamma * log2f(sh0));
      const float wp1 = exp2f(gamma * log2f(sh1));
      const float itot = 1.f / (allsum(wp0 + wp1) + EPSF);
      wprev[n0] = wp0 * itot;
      wprev[n1] = wp1 * itot;
    }
    __syncthreads();  // b8
  }
}

extern "C" void kernel_launch(void* const* d_in, const int* in_sizes, int n_in,
                              void* d_out, int out_size, void* d_ws, size_t ws_size,
                              hipStream_t stream) {
  const float* x    = (const float*)d_in[0];
  const float* mem0 = (const float*)d_in[1];
  const float* wr0  = (const float*)d_in[2];
  const float* ww0  = (const float*)d_in[3];
  const float* h0   = (const float*)d_in[4];
  const float* Wx   = (const float*)d_in[5];
  const float* Wrd  = (const float*)d_in[6];
  const float* bh   = (const float*)d_in[7];
  const float* Wk   = (const float*)d_in[8];
  const float* bk   = (const float*)d_in[9];
  const float* Wb   = (const float*)d_in[10];
  const float* bb   = (const float*)d_in[11];
  const float* Wg   = (const float*)d_in[12];
  const float* bg   = (const float*)d_in[13];
  const float* Ws   = (const float*)d_in[14];
  const float* bs   = (const float*)d_in[15];
  const float* Wgam = (const float*)d_in[16];
  const float* bgam = (const float*)d_in[17];
  const float* We   = (const float*)d_in[18];
  const float* be   = (const float*)d_in[19];
  const float* Wa   = (const float*)d_in[20];
  const float* ba   = (const float*)d_in[21];
  float* out = (float*)d_out;
  unsigned int* wsb = (unsigned int*)d_ws;   // 98304 uints = 384 KB

  hipLaunchKernelGGL(ntm_prep, dim3(384), dim3(256), 0, stream, We, Wa, Wk, Wx, Wrd, wsb);
  hipLaunchKernelGGL(ntm_kernel, dim3(64), dim3(NT), 0, stream,
                     x, mem0, wr0, ww0, h0, bh, bk, Wb, bb,
                     Wg, bg, Ws, bs, Wgam, bgam, be, ba,
                     (const uint4*)wsb, out);
}

// Round 14
// 1209.886 us; speedup vs baseline: 4.4320x; 4.4320x over previous
//
#include <hip/hip_runtime.h>
#include <math.h>

#define Tt 128
#define NT 512
#define EPSF 1e-8f
#define WC_OFF 65536   // u32 offset of C-matmul weights in wsb

typedef _Float16 f16x2 __attribute__((ext_vector_type(2)));

__device__ __forceinline__ float fsigmoid(float v) { return 1.f / (1.f + expf(-v)); }
__device__ __forceinline__ float fsoftplus(float v) { return (v > 20.f) ? v : log1pf(expf(v)); }
__device__ __forceinline__ float ftanh(float v) { float e = expf(2.f * v); return 1.f - 2.f / (e + 1.f); }

__device__ __forceinline__ float dot2(f16x2 a, f16x2 b, float c) {
#if __has_builtin(__builtin_amdgcn_fdot2)
  return __builtin_amdgcn_fdot2(a, b, c, false);
#else
  return c + (float)a.x * (float)b.x + (float)a.y * (float)b.y;
#endif
}
__device__ __forceinline__ f16x2 pack2(float a, float b) {
  f16x2 p; p.x = (_Float16)a; p.y = (_Float16)b; return p;
}
__device__ __forceinline__ f16x2 bc16(unsigned int v) { return __builtin_bit_cast(f16x2, v); }

// ---- DPP reduction primitives ----
template <int C> __device__ __forceinline__ float dppadd(float v) {
  int s = __builtin_amdgcn_update_dpp(0, __builtin_bit_cast(int, v), C, 0xf, 0xf, true);
  return v + __builtin_bit_cast(float, s);
}
template <int C> __device__ __forceinline__ float dppmax(float v) {
  int iv = __builtin_bit_cast(int, v);
  int s = __builtin_amdgcn_update_dpp(iv, iv, C, 0xf, 0xf, false);
  return fmaxf(v, __builtin_bit_cast(float, s));
}
__device__ __forceinline__ float qsum16(float v) {
  v = dppadd<0x111>(v); v = dppadd<0x112>(v); v = dppadd<0x114>(v); v = dppadd<0x118>(v);
  return v;
}
__device__ __forceinline__ float halfsum(float v) {  // lane31/63 hold 32-lane sums
  v = qsum16(v); v = dppadd<0x142>(v);
  return v;
}
__device__ __forceinline__ float allsum(float v) {
  v = halfsum(v); v = dppadd<0x143>(v);
  return __builtin_bit_cast(float, __builtin_amdgcn_readlane(__builtin_bit_cast(int, v), 63));
}
__device__ __forceinline__ float allmax(float v) {
  v = dppmax<0x111>(v); v = dppmax<0x112>(v); v = dppmax<0x114>(v);
  v = dppmax<0x118>(v); v = dppmax<0x142>(v); v = dppmax<0x143>(v);
  return __builtin_bit_cast(float, __builtin_amdgcn_readlane(__builtin_bit_cast(int, v), 63));
}

// ===== prep: pack f32 weights -> f16x2 in column-owner streaming layouts =====
// big4 [0,65536):  i = (q*512 + col)*4 + e ; q in 0..31 -> K elems (8q+2e, 8q+2e+1)
//   of column col in [We|Wa|Wk0|Wk1] (col>>7 selects matrix, col&127 its column)
// wc [65536,98304): i = WC_OFF + ((q*2+kh)*256 + col)*4 + e ; q in 0..15
//   K = kh*128 + 8q + 2e over [x|r]: K<128 -> Wx[K][col], else Wrd[K-128][col]
__global__ __launch_bounds__(256, 1) void ntm_prep(
    const float* __restrict__ We, const float* __restrict__ Wa,
    const float* __restrict__ Wk, const float* __restrict__ Wx,
    const float* __restrict__ Wrd, unsigned int* __restrict__ wsb)
{
  const int i = blockIdx.x * 256 + threadIdx.x;   // grid 384*256 = 98304
  if (i < 65536) {
    const int e = i & 3;
    const int col = (i >> 2) & 511;
    const int q = i >> 11;
    const int k0 = 8 * q + 2 * e;
    const int mat = col >> 7;
    const int mcol = col & 127;
    const float* base = (mat == 0) ? We : (mat == 1) ? Wa : (mat == 2) ? Wk : (Wk + 256 * 128);
    wsb[i] = __builtin_bit_cast(unsigned int,
               pack2(base[k0 * 128 + mcol], base[(k0 + 1) * 128 + mcol]));
  } else {
    const int j = i - WC_OFF;
    const int e = j & 3;
    const int col = (j >> 2) & 255;
    const int kh = (j >> 10) & 1;
    const int q = j >> 11;
    const int k0 = kh * 128 + 8 * q + 2 * e;
    float v0, v1;
    if (k0 < 128) { v0 = Wx[k0 * 256 + col]; v1 = Wx[(k0 + 1) * 256 + col]; }
    else          { v0 = Wrd[(k0 - 128) * 256 + col]; v1 = Wrd[(k0 - 127) * 256 + col]; }
    wsb[i] = __builtin_bit_cast(unsigned int, pack2(v0, v1));
  }
}

__global__ __launch_bounds__(NT, 1) void ntm_kernel(
    const float* __restrict__ x, const float* __restrict__ mem0,
    const float* __restrict__ wr0, const float* __restrict__ ww0,
    const float* __restrict__ h0, const float* __restrict__ bh,
    const float* __restrict__ bk,
    const float* __restrict__ Wb, const float* __restrict__ bb,
    const float* __restrict__ Wg, const float* __restrict__ bg,
    const float* __restrict__ Ws, const float* __restrict__ bs,
    const float* __restrict__ Wgam, const float* __restrict__ bgam,
    const float* __restrict__ be, const float* __restrict__ ba,
    const uint4* __restrict__ wsb4,
    float* __restrict__ out)
{
  const int b = blockIdx.x;
  const int t = threadIdx.x;
  const int lane = t & 63;
  const int wave = t >> 6;
  const int c4 = t & 31;    // 4-col group for mem passes
  const int rs = t >> 5;    // row slice (16): rows rs, rs+16, ..., rs+112

  __shared__ __align__(16) float part[2048];      // P1 r-partials (2048) / P3 partials (512)
  __shared__ __align__(16) float h_l[256];
  __shared__ __align__(16) unsigned int h16[128]; // h packed f16x2 (as 32 uint4)
  __shared__ __align__(16) unsigned int xr16[128];// [x|r] packed f16x2 (as 32 uint4)
  __shared__ __align__(16) float er[128];
  __shared__ __align__(16) float ad[128];
  __shared__ __align__(16) float kbuf[256];
  __shared__ float wsm_l[3072];
  __shared__ float wr_s[128], ww_s[128];
  __shared__ float normsq[128];
  __shared__ float dotv[256];
  __shared__ float scal[12];
  __shared__ float red2[4];
  __shared__ float bias_big[512];                 // [be | ba | bk0 | bk1]
  __shared__ float bh_l[256];
  __shared__ float bias_sm[12];

  // ===== NTM memory tensor lives in REGISTERS: rows rs+16k, cols c4*4..c4*4+3
  float4 memreg[8];
  #pragma unroll
  for (int k = 0; k < 8; ++k)
    memreg[k] = *reinterpret_cast<const float4*>(&mem0[(rs + 16 * k) * 128 + c4 * 4]);

  // ===== state / bias init =====
  if (t < 128) { wr_s[t] = wr0[b * 128 + t]; ww_s[t] = ww0[b * 128 + t]; }
  if (t < 256) {
    float v = h0[b * 256 + t];
    h_l[t] = v; bh_l[t] = bh[t];
    const float vo = __shfl_xor(v, 1);
    if (!(t & 1)) h16[t >> 1] = __builtin_bit_cast(unsigned int, pack2(v, vo));
  }
  bias_big[t] = (t < 128) ? be[t] : (t < 256) ? ba[t - 128] : bk[t - 256];
  for (int i = t; i < 3072; i += NT) {
    const int d = i >> 8, j = i & 255;
    const int head = d / 6, kind = d % 6;
    float v;
    if (kind == 0)      v = Wb[head * 256 + j];
    else if (kind == 1) v = Wg[head * 256 + j];
    else if (kind == 2) v = Wgam[head * 256 + j];
    else                v = Ws[head * 768 + j * 3 + (kind - 3)];
    wsm_l[i] = v;
  }
  if (t < 12) {
    const int head = t / 6, kind = t % 6;
    bias_sm[t] = (kind == 0) ? bb[head] : (kind == 1) ? bg[head]
               : (kind == 2) ? bgam[head] : bs[head * 3 + (kind - 3)];
  }
  __syncthreads();

  const uint4* h16_4 = reinterpret_cast<const uint4*>(h16);
  const uint4* xr16_4 = reinterpret_cast<const uint4*>(xr16);

  // ---- P5: column-owner big4 (thread t = output col t of [er'|ad'|k0|k1])
  //          + k^2 DPP + 12 small dots. Single phase, no partials.
  auto phase_big4 = [&]() {
    float a0 = 0.f, a1 = 0.f, a2 = 0.f, a3 = 0.f;
    const uint4* wp = wsb4 + t;
    #pragma unroll
    for (int q = 0; q < 32; ++q) {
      const uint4 w = wp[q * 512];
      const uint4 hq = h16_4[q];        // wave-uniform -> LDS broadcast
      a0 = dot2(bc16(hq.x), bc16(w.x), a0);
      a1 = dot2(bc16(hq.y), bc16(w.y), a1);
      a2 = dot2(bc16(hq.z), bc16(w.z), a2);
      a3 = dot2(bc16(hq.w), bc16(w.w), a3);
    }
    const float acc = (a0 + a1) + (a2 + a3) + bias_big[t];
    if (t < 128)      er[t] = fsigmoid(acc);
    else if (t < 256) ad[t - 128] = ftanh(acc);
    else {
      const float kv = ftanh(acc);
      kbuf[t - 256] = kv;
      float ks = kv * kv;
      ks = halfsum(ks); ks = dppadd<0x143>(ks);
      if (lane == 63) red2[wave - 4] = ks;
    }
    if (t < 192) {   // 12 small dots (beta,g,gamma,s0..2 x 2 heads), 16 lanes each
      const int d = t >> 4, l4 = t & 15;
      float s = 0.f;
      #pragma unroll
      for (int q = 0; q < 16; ++q) s += h_l[l4 + 16 * q] * wsm_l[d * 256 + l4 + 16 * q];
      s = qsum16(s);
      if ((lane & 15) == 15) scal[d] = s + bias_sm[d];
    }
  };

  // prologue: er/ad/k/scal for step 0 from h0
  phase_big4();
  __syncthreads();

  for (int step = 0; step < Tt; ++step) {
    // ---- P1: x load+pack; reg-resident mem erase/add; r partials
    if (t < 64) {
      const float2 xv = reinterpret_cast<const float2*>(x + ((size_t)b * Tt + step) * 128)[t];
      xr16[t] = __builtin_bit_cast(unsigned int, pack2(xv.x, xv.y));
    }
    {
      const float4 e4 = *reinterpret_cast<const float4*>(&er[c4 * 4]);
      const float4 a4 = *reinterpret_cast<const float4*>(&ad[c4 * 4]);
      float rx = 0.f, ry = 0.f, rz = 0.f, rw = 0.f;
      #pragma unroll
      for (int k = 0; k < 8; ++k) {
        const int n = rs + 16 * k;
        const float wwn = ww_s[n], wrn = wr_s[n];
        float4 v = memreg[k];
        v.x = v.x * (1.f - wwn * e4.x) + wwn * a4.x;
        v.y = v.y * (1.f - wwn * e4.y) + wwn * a4.y;
        v.z = v.z * (1.f - wwn * e4.z) + wwn * a4.z;
        v.w = v.w * (1.f - wwn * e4.w) + wwn * a4.w;
        memreg[k] = v;
        rx += wrn * v.x; ry += wrn * v.y; rz += wrn * v.z; rw += wrn * v.w;
      }
      *reinterpret_cast<float4*>(&part[t * 4]) = make_float4(rx, ry, rz, rw);
    }
    __syncthreads();  // b1

    // ---- P2: reduce r partials; pack into xr16[64..127]
    if (t < 128) {
      float r = 0.f;
      #pragma unroll
      for (int s = 0; s < 16; ++s) r += part[s * 128 + t];
      const float ro = __shfl_xor(r, 1);
      if (!(t & 1)) xr16[64 + (t >> 1)] = __builtin_bit_cast(unsigned int, pack2(r, ro));
    }
    __syncthreads();  // b2

    // ---- P3: C-matmul, 2 threads/col (K halves), weights streamed
    {
      const int col = t & 255, kh = t >> 8;
      float a0 = 0.f, a1 = 0.f, a2 = 0.f, a3 = 0.f;
      const uint4* wp = wsb4 + (WC_OFF / 4) + kh * 256 + col;
      #pragma unroll
      for (int q = 0; q < 16; ++q) {
        const uint4 w = wp[q * 512];
        const uint4 xq = xr16_4[kh * 16 + q];
        a0 = dot2(bc16(xq.x), bc16(w.x), a0);
        a1 = dot2(bc16(xq.y), bc16(w.y), a1);
        a2 = dot2(bc16(xq.z), bc16(w.z), a2);
        a3 = dot2(bc16(xq.w), bc16(w.w), a3);
      }
      part[t] = (a0 + a1) + (a2 + a3);
    }
    __syncthreads();  // b3

    // ---- P4: h = tanh(.); write out; pack h16
    if (t < 256) {
      float v = bh_l[t] + part[t] + part[t + 256];
      v = ftanh(v);
      h_l[t] = v;
      out[((size_t)b * Tt + step) * 256 + t] = v;
      const float vo = __shfl_xor(v, 1);
      if (!(t & 1)) h16[t >> 1] = __builtin_bit_cast(unsigned int, pack2(v, vo));
    }
    __syncthreads();  // b4

    // ---- P5: big4 column-owner + k^2 + small dots from new h
    phase_big4();
    __syncthreads();  // b5

    // ---- P7: content dots (both heads) + normsq on reg-resident mem
    {
      const float4 k40 = *reinterpret_cast<const float4*>(&kbuf[c4 * 4]);
      const float4 k41 = *reinterpret_cast<const float4*>(&kbuf[128 + c4 * 4]);
      float d0[8], d1[8], nq[8];
      #pragma unroll
      for (int k = 0; k < 8; ++k) {
        const float4 v = memreg[k];
        d0[k] = k40.x * v.x + k40.y * v.y + k40.z * v.z + k40.w * v.w;
        d1[k] = k41.x * v.x + k41.y * v.y + k41.z * v.z + k41.w * v.w;
        nq[k] = v.x * v.x + v.y * v.y + v.z * v.z + v.w * v.w;
      }
      #pragma unroll
      for (int k = 0; k < 8; ++k) { d0[k] = halfsum(d0[k]); d1[k] = halfsum(d1[k]); nq[k] = halfsum(nq[k]); }
      if ((lane & 31) == 31) {
        #pragma unroll
        for (int k = 0; k < 8; ++k) {
          const int n = rs + 16 * k;
          dotv[n] = d0[k]; dotv[128 + n] = d1[k]; normsq[n] = nq[k];
        }
      }
    }
    __syncthreads();  // b7

    // ---- P8: addressing tail, wave0=head0, wave1=head1 (DPP all-reduces)
    if (wave < 2) {
      const int head = wave;
      const int h6 = head * 6;
      const float beta  = fsoftplus(scal[h6]);
      const float g     = fsigmoid(scal[h6 + 1]);
      const float gamma = 1.f + fsoftplus(scal[h6 + 2]);
      float e0 = scal[h6 + 3], e1 = scal[h6 + 4], e2 = scal[h6 + 5];
      const float mx3 = fmaxf(e0, fmaxf(e1, e2));
      float x0 = expf(e0 - mx3), x1 = expf(e1 - mx3), x2 = expf(e2 - mx3);
      const float si = 1.f / (x0 + x1 + x2);
      const float s0 = x0 * si, s1 = x1 * si, s2 = x2 * si;
      const float knorm = sqrtf(red2[2 * head] + red2[2 * head + 1]);
      float* wprev = head ? ww_s : wr_s;
      const int n0 = 2 * lane, n1 = 2 * lane + 1;
      float l0 = beta * dotv[head * 128 + n0] / (knorm * sqrtf(normsq[n0]) + EPSF);
      float l1 = beta * dotv[head * 128 + n1] / (knorm * sqrtf(normsq[n1]) + EPSF);
      const float mx = allmax(fmaxf(l0, l1));
      float q0 = expf(l0 - mx), q1 = expf(l1 - mx);
      const float inv = 1.f / allsum(q0 + q1);
      const float wg0 = g * q0 * inv + (1.f - g) * wprev[n0];
      const float wg1 = g * q1 * inv + (1.f - g) * wprev[n1];
      const float wgl = __shfl(wg1, (lane + 63) & 63);
      const float wgr = __shfl(wg0, (lane + 1) & 63);
      const float sh0 = s0 * wgl + s1 * wg0 + s2 * wg1;
      const float sh1 = s0 * wg0 + s1 * wg1 + s2 * wgr;
      const float wp0 = exp2f(gamma * log2f(sh0));
      const float wp1 = exp2f(gamma * log2f(sh1));
      const float itot = 1.f / (allsum(wp0 + wp1) + EPSF);
      wprev[n0] = wp0 * itot;
      wprev[n1] = wp1 * itot;
    }
    __syncthreads();  // b8
  }
}

extern "C" void kernel_launch(void* const* d_in, const int* in_sizes, int n_in,
                              void* d_out, int out_size, void* d_ws, size_t ws_size,
                              hipStream_t stream) {
  const float* x    = (const float*)d_in[0];
  const float* mem0 = (const float*)d_in[1];
  const float* wr0  = (const float*)d_in[2];
  const float* ww0  = (const float*)d_in[3];
  const float* h0   = (const float*)d_in[4];
  const float* Wx   = (const float*)d_in[5];
  const float* Wrd  = (const float*)d_in[6];
  const float* bh   = (const float*)d_in[7];
  const float* Wk   = (const float*)d_in[8];
  const float* bk   = (const float*)d_in[9];
  const float* Wb   = (const float*)d_in[10];
  const float* bb   = (const float*)d_in[11];
  const float* Wg   = (const float*)d_in[12];
  const float* bg   = (const float*)d_in[13];
  const float* Ws   = (const float*)d_in[14];
  const float* bs   = (const float*)d_in[15];
  const float* Wgam = (const float*)d_in[16];
  const float* bgam = (const float*)d_in[17];
  const float* We   = (const float*)d_in[18];
  const float* be   = (const float*)d_in[19];
  const float* Wa   = (const float*)d_in[20];
  const float* ba   = (const float*)d_in[21];
  float* out = (float*)d_out;
  unsigned int* wsb = (unsigned int*)d_ws;   // 98304 uints = 384 KB

  hipLaunchKernelGGL(ntm_prep, dim3(384), dim3(256), 0, stream, We, Wa, Wk, Wx, Wrd, wsb);
  hipLaunchKernelGGL(ntm_kernel, dim3(128), dim3(NT), 0, stream,
                     x, mem0, wr0, ww0, h0, bh, bk, Wb, bb,
                     Wg, bg, Ws, bs, Wgam, bgam, be, ba,
                     (const uint4*)wsb, out);
}

// Round 16
// 834.287 us; speedup vs baseline: 6.4273x; 1.4502x over previous
//
#include <hip/hip_runtime.h>
#include <math.h>

#define Tt 128
#define NT 512
#define EPSF 1e-8f

typedef _Float16 f16x2 __attribute__((ext_vector_type(2)));

__device__ __forceinline__ float fsigmoid(float v) { return 1.f / (1.f + expf(-v)); }
__device__ __forceinline__ float fsoftplus(float v) { return (v > 20.f) ? v : log1pf(expf(v)); }
__device__ __forceinline__ float ftanh(float v) { float e = expf(2.f * v); return 1.f - 2.f / (e + 1.f); }

__device__ __forceinline__ float dot2(f16x2 a, f16x2 b, float c) {
#if __has_builtin(__builtin_amdgcn_fdot2)
  return __builtin_amdgcn_fdot2(a, b, c, false);
#else
  return c + (float)a.x * (float)b.x + (float)a.y * (float)b.y;
#endif
}
__device__ __forceinline__ f16x2 pack2(float a, float b) {
  f16x2 p; p.x = (_Float16)a; p.y = (_Float16)b; return p;
}
__device__ __forceinline__ f16x2 bc16(unsigned int v) { return __builtin_bit_cast(f16x2, v); }

// ---- DPP reduction primitives ----
template <int C> __device__ __forceinline__ float dppadd(float v) {
  int s = __builtin_amdgcn_update_dpp(0, __builtin_bit_cast(int, v), C, 0xf, 0xf, true);
  return v + __builtin_bit_cast(float, s);
}
template <int C> __device__ __forceinline__ float dppmax(float v) {
  int iv = __builtin_bit_cast(int, v);
  int s = __builtin_amdgcn_update_dpp(iv, iv, C, 0xf, 0xf, false);
  return fmaxf(v, __builtin_bit_cast(float, s));
}
__device__ __forceinline__ float qsum16(float v) {
  v = dppadd<0x111>(v); v = dppadd<0x112>(v); v = dppadd<0x114>(v); v = dppadd<0x118>(v);
  return v;
}
__device__ __forceinline__ float halfsum(float v) {
  v = qsum16(v); v = dppadd<0x142>(v);
  return v;
}
__device__ __forceinline__ float allsum(float v) {
  v = halfsum(v); v = dppadd<0x143>(v);
  return __builtin_bit_cast(float, __builtin_amdgcn_readlane(__builtin_bit_cast(int, v), 63));
}
__device__ __forceinline__ float allmax(float v) {
  v = dppmax<0x111>(v); v = dppmax<0x112>(v); v = dppmax<0x114>(v);
  v = dppmax<0x118>(v); v = dppmax<0x142>(v); v = dppmax<0x143>(v);
  return __builtin_bit_cast(float, __builtin_amdgcn_readlane(__builtin_bit_cast(int, v), 63));
}

// ===== prep: pack big4 weights [We|Wa|Wk0|Wk1] f32 -> f16x2 (round-10 layout) =====
// uint index i = (((c*8 + js)*4 + jj4)*64 + cg)*4 + e ; jj = jj4*4+e
// value = pack2(W[row0*128+col], W[(row0+1)*128+col]), row0 = js*32+2*jj, col=(c&1)*64+cg
__global__ __launch_bounds__(512, 1) void ntm_prep(
    const float* __restrict__ We, const float* __restrict__ Wa,
    const float* __restrict__ Wk, unsigned int* __restrict__ wsb)
{
  const int i = blockIdx.x * 512 + threadIdx.x;   // grid 128*512 = 65536
  const int e = i & 3;
  const int cg = (i >> 2) & 63;
  const int jj4 = (i >> 8) & 3;
  const int js = (i >> 10) & 7;
  const int c = (i >> 13) & 7;
  const int jj = jj4 * 4 + e;
  const int mat = c >> 1;
  const int col = (c & 1) * 64 + cg;
  const int row0 = js * 32 + 2 * jj;
  const float* base = (mat == 0) ? We : (mat == 1) ? Wa : (mat == 2) ? Wk : (Wk + 256 * 128);
  wsb[i] = __builtin_bit_cast(unsigned int, pack2(base[row0 * 128 + col], base[(row0 + 1) * 128 + col]));
}

__global__ __launch_bounds__(NT, 1) void ntm_kernel(
    const float* __restrict__ x, const float* __restrict__ mem0,
    const float* __restrict__ wr0, const float* __restrict__ ww0,
    const float* __restrict__ h0, const float* __restrict__ Wx,
    const float* __restrict__ Wrd, const float* __restrict__ bh,
    const float* __restrict__ bk,
    const float* __restrict__ Wb, const float* __restrict__ bb,
    const float* __restrict__ Wg, const float* __restrict__ bg,
    const float* __restrict__ Ws, const float* __restrict__ bs,
    const float* __restrict__ Wgam, const float* __restrict__ bgam,
    const float* __restrict__ be, const float* __restrict__ ba,
    const uint4* __restrict__ wsb4,
    float* __restrict__ out)
{
  const int b = blockIdx.x;
  const int t = threadIdx.x;
  const int lane = t & 63;
  const int wave = t >> 6;
  const int cg = t & 63;    // matmul column lane
  const int js = t >> 6;    // inner-dim slice (8 slices of 32)
  const int c4 = t & 31;    // float4 column group for mem passes
  const int rs = t >> 5;    // row slice for mem passes (16 slices)

  __shared__ __align__(16) float mem[128 * 128];   // 64 KB
  __shared__ __align__(16) uint4 lbig7[2048];      // 32 KB: big4 c=7 block cached in LDS
  __shared__ __align__(16) float part[4096];       // 16 KB
  __shared__ __align__(16) float h_l[256];
  __shared__ __align__(16) float xf[128];
  __shared__ __align__(16) float rf[128];
  __shared__ __align__(16) float er[128];
  __shared__ __align__(16) float ad[128];
  __shared__ __align__(16) float kbuf[256];
  __shared__ float wsm_l[3072];
  __shared__ float wr_s[128], ww_s[128];
  __shared__ float normsq[128];
  __shared__ float dotv[256];
  __shared__ float scal[12];
  __shared__ float red2[4];
  __shared__ float bias_big[512];                  // [be | ba | bk0 | bk1]
  __shared__ float bh_l[256];
  __shared__ float bias_sm[12];

  // ===== C-matmul weights resident in regs: 64 f16x2 (fits 128-reg cap w/o spill)
  f16x2 wcreg[64];
  {
    const float* basep = (js < 4) ? (Wx + (js * 32) * 256) : (Wrd + ((js - 4) * 32) * 256);
    #pragma unroll
    for (int c = 0; c < 4; ++c) {
      const float* bp = basep + c * 64 + cg;
      #pragma unroll
      for (int jj = 0; jj < 16; ++jj) {
        wcreg[c * 16 + jj] = pack2(bp[(2 * jj) * 256], bp[(2 * jj + 1) * 256]);
      }
    }
  }

  // ===== state / bias / small-weight / LDS-weight init =====
  for (int i = t; i < 128 * 128; i += NT) mem[i] = mem0[i];
  for (int i = t; i < 2048; i += NT) lbig7[i] = wsb4[14336 + i];  // c=7: uint4 idx 14336..16383
  if (t < 128) { wr_s[t] = wr0[b * 128 + t]; ww_s[t] = ww0[b * 128 + t]; }
  if (t < 256) { h_l[t] = h0[b * 256 + t]; bh_l[t] = bh[t]; }
  bias_big[t] = (t < 128) ? be[t] : (t < 256) ? ba[t - 128] : bk[t - 256];
  for (int i = t; i < 3072; i += NT) {
    const int d = i >> 8, j = i & 255;
    const int head = d / 6, kind = d % 6;
    float v;
    if (kind == 0)      v = Wb[head * 256 + j];
    else if (kind == 1) v = Wg[head * 256 + j];
    else if (kind == 2) v = Wgam[head * 256 + j];
    else                v = Ws[head * 768 + j * 3 + (kind - 3)];
    wsm_l[i] = v;
  }
  if (t < 12) {
    const int head = t / 6, kind = t % 6;
    bias_sm[t] = (kind == 0) ? bb[head] : (kind == 1) ? bg[head]
               : (kind == 2) ? bgam[head] : bs[head * 3 + (kind - 3)];
  }
  __syncthreads();

  // c=0 prefetch registers (issued early each step, consumed in phase_big4)
  uint4 pf0, pf1, pf2, pf3;
  auto issue_pf = [&]() {
    const uint4* p0 = wsb4 + js * 256 + cg;   // c=0 block
    pf0 = p0[0]; pf1 = p0[64]; pf2 = p0[128]; pf3 = p0[192];
  };

  // ---- big4 matmul partials: c=0 from pf regs, c=1..6 streamed L2, c=7 from LDS
  auto phase_big4 = [&]() {
    f16x2 hh[16];
    #pragma unroll
    for (int jj = 0; jj < 16; ++jj) {
      const float2 h2 = *reinterpret_cast<const float2*>(&h_l[js * 32 + 2 * jj]);
      hh[jj] = pack2(h2.x, h2.y);
    }
    float acc[8];
    #pragma unroll
    for (int c = 0; c < 8; ++c) acc[c] = 0.f;
    #pragma unroll
    for (int c = 0; c < 8; ++c) {
      uint4 w0, w1, w2, w3;
      if (c == 0) { w0 = pf0; w1 = pf1; w2 = pf2; w3 = pf3; }
      else if (c == 7) {
        const uint4* p = lbig7 + js * 256 + cg;
        w0 = p[0]; w1 = p[64]; w2 = p[128]; w3 = p[192];
      } else {
        const uint4* p = wsb4 + (c * 8 + js) * 256 + cg;
        w0 = p[0]; w1 = p[64]; w2 = p[128]; w3 = p[192];
      }
      acc[c] = dot2(hh[0],  bc16(w0.x), acc[c]);
      acc[c] = dot2(hh[1],  bc16(w0.y), acc[c]);
      acc[c] = dot2(hh[2],  bc16(w0.z), acc[c]);
      acc[c] = dot2(hh[3],  bc16(w0.w), acc[c]);
      acc[c] = dot2(hh[4],  bc16(w1.x), acc[c]);
      acc[c] = dot2(hh[5],  bc16(w1.y), acc[c]);
      acc[c] = dot2(hh[6],  bc16(w1.z), acc[c]);
      acc[c] = dot2(hh[7],  bc16(w1.w), acc[c]);
      acc[c] = dot2(hh[8],  bc16(w2.x), acc[c]);
      acc[c] = dot2(hh[9],  bc16(w2.y), acc[c]);
      acc[c] = dot2(hh[10], bc16(w2.z), acc[c]);
      acc[c] = dot2(hh[11], bc16(w2.w), acc[c]);
      acc[c] = dot2(hh[12], bc16(w3.x), acc[c]);
      acc[c] = dot2(hh[13], bc16(w3.y), acc[c]);
      acc[c] = dot2(hh[14], bc16(w3.z), acc[c]);
      acc[c] = dot2(hh[15], bc16(w3.w), acc[c]);
    }
    #pragma unroll
    for (int c = 0; c < 8; ++c) part[js * 512 + c * 64 + cg] = acc[c];
  };

  // ---- reduce big4 -> er/ad/kbuf + k^2 (DPP) + 12 small dots (DPP)
  auto phase_reduce = [&]() {
    {
      float v = bias_big[t];
      #pragma unroll
      for (int s = 0; s < 8; ++s) v += part[s * 512 + t];
      if (t < 128)      er[t] = fsigmoid(v);
      else if (t < 256) ad[t - 128] = ftanh(v);
      else {
        float kv = ftanh(v);
        kbuf[t - 256] = kv;
        float ks = kv * kv;
        ks = halfsum(ks); ks = dppadd<0x143>(ks);
        if (lane == 63) red2[wave - 4] = ks;
      }
    }
    if (t < 384) {
      const int d = t >> 5, l5 = t & 31;
      float s = 0.f;
      #pragma unroll
      for (int q = 0; q < 8; ++q) s += h_l[l5 + 32 * q] * wsm_l[d * 256 + l5 + 32 * q];
      s = halfsum(s);
      if ((lane & 31) == 31) scal[d] = s + bias_sm[d];
    }
  };

  // prologue: er/ad/k/scal for step 0 from h0
  issue_pf();
  phase_big4();
  __syncthreads();
  phase_reduce();
  __syncthreads();

  for (int step = 0; step < Tt; ++step) {
    // ---- issue c=0 prefetch for this step's P5 (L2 port works during P1-P4)
    issue_pf();

    // ---- P1: x_t -> xf; mem erase/add update; r partials
    if (t < 128) xf[t] = x[((size_t)b * Tt + step) * 128 + t];
    {
      const float4 e4 = *reinterpret_cast<const float4*>(&er[c4 * 4]);
      const float4 a4 = *reinterpret_cast<const float4*>(&ad[c4 * 4]);
      float rx = 0.f, ry = 0.f, rz = 0.f, rw = 0.f;
      #pragma unroll
      for (int k = 0; k < 8; ++k) {
        const int n = rs + 16 * k;
        const float wwn = ww_s[n], wrn = wr_s[n];
        float4 v = *reinterpret_cast<const float4*>(&mem[n * 128 + c4 * 4]);
        v.x = v.x * (1.f - wwn * e4.x) + wwn * a4.x;
        v.y = v.y * (1.f - wwn * e4.y) + wwn * a4.y;
        v.z = v.z * (1.f - wwn * e4.z) + wwn * a4.z;
        v.w = v.w * (1.f - wwn * e4.w) + wwn * a4.w;
        *reinterpret_cast<float4*>(&mem[n * 128 + c4 * 4]) = v;
        rx += wrn * v.x; ry += wrn * v.y; rz += wrn * v.z; rw += wrn * v.w;
      }
      *reinterpret_cast<float4*>(&part[rs * 128 + c4 * 4]) = make_float4(rx, ry, rz, rw);
    }
    __syncthreads();  // b1

    // ---- P2: reduce r partials
    if (t < 128) {
      float r = 0.f;
      #pragma unroll
      for (int s = 0; s < 16; ++s) r += part[s * 128 + t];
      rf[t] = r;
    }
    __syncthreads();  // b2

    // ---- P3: C-matmul partials from [xf|rf] (reg-resident weights)
    {
      const float* src = (js < 4) ? (xf + js * 32) : (rf + (js - 4) * 32);
      float acc[4];
      #pragma unroll
      for (int c = 0; c < 4; ++c) acc[c] = 0.f;
      #pragma unroll
      for (int jj = 0; jj < 16; ++jj) {
        const float2 s2 = *reinterpret_cast<const float2*>(&src[2 * jj]);
        const f16x2 xx = pack2(s2.x, s2.y);
        #pragma unroll
        for (int c = 0; c < 4; ++c) acc[c] = dot2(xx, wcreg[c * 16 + jj], acc[c]);
      }
      #pragma unroll
      for (int c = 0; c < 4; ++c) part[js * 256 + c * 64 + cg] = acc[c];
    }
    __syncthreads();  // b3

    // ---- P4: h = tanh(.); write out
    if (t < 256) {
      float v = bh_l[t];
      #pragma unroll
      for (int s = 0; s < 8; ++s) v += part[s * 256 + t];
      v = ftanh(v);
      h_l[t] = v;
      out[((size_t)b * Tt + step) * 256 + t] = v;
    }
    __syncthreads();  // b4

    // ---- P5/P6: big4 + reduce from new h
    phase_big4();
    __syncthreads();  // b5
    phase_reduce();
    __syncthreads();  // b6

    // ---- P7: content dots + row normsq fused (DPP half-reduction)
    {
      const int head = t >> 8;           // waves 0-3: head0, 4-7: head1
      const int u = t & 255;
      const int cc = u & 31, ns = u >> 5; // half-wave owns 16 rows
      const float4 k4 = *reinterpret_cast<const float4*>(&kbuf[head * 128 + cc * 4]);
      #pragma unroll
      for (int ch = 0; ch < 2; ++ch) {
        float dsum[8], qsum[8];
        #pragma unroll
        for (int ii = 0; ii < 8; ++ii) {
          const int n = ns * 16 + ch * 8 + ii;
          const float4 m4 = *reinterpret_cast<const float4*>(&mem[n * 128 + cc * 4]);
          dsum[ii] = k4.x * m4.x + k4.y * m4.y + k4.z * m4.z + k4.w * m4.w;
          qsum[ii] = m4.x * m4.x + m4.y * m4.y + m4.z * m4.z + m4.w * m4.w;
        }
        #pragma unroll
        for (int ii = 0; ii < 8; ++ii) dsum[ii] = halfsum(dsum[ii]);
        if (head == 0) {
          #pragma unroll
          for (int ii = 0; ii < 8; ++ii) qsum[ii] = halfsum(qsum[ii]);
        }
        if ((lane & 31) == 31) {
          #pragma unroll
          for (int ii = 0; ii < 8; ++ii) dotv[head * 128 + ns * 16 + ch * 8 + ii] = dsum[ii];
          if (head == 0) {
            #pragma unroll
            for (int ii = 0; ii < 8; ++ii) normsq[ns * 16 + ch * 8 + ii] = qsum[ii];
          }
        }
      }
    }
    __syncthreads();  // b7

    // ---- P8: addressing tail, wave0=head0, wave1=head1 (DPP all-reduces)
    if (wave < 2) {
      const int head = wave;
      const int h6 = head * 6;
      const float beta  = fsoftplus(scal[h6]);
      const float g     = fsigmoid(scal[h6 + 1]);
      const float gamma = 1.f + fsoftplus(scal[h6 + 2]);
      float e0 = scal[h6 + 3], e1 = scal[h6 + 4], e2 = scal[h6 + 5];
      const float mx3 = fmaxf(e0, fmaxf(e1, e2));
      float x0 = expf(e0 - mx3), x1 = expf(e1 - mx3), x2 = expf(e2 - mx3);
      const float si = 1.f / (x0 + x1 + x2);
      const float s0 = x0 * si, s1 = x1 * si, s2 = x2 * si;
      const float knorm = sqrtf(red2[2 * head] + red2[2 * head + 1]);
      float* wprev = head ? ww_s : wr_s;
      const int n0 = 2 * lane, n1 = 2 * lane + 1;
      float l0 = beta * dotv[head * 128 + n0] / (knorm * sqrtf(normsq[n0]) + EPSF);
      float l1 = beta * dotv[head * 128 + n1] / (knorm * sqrtf(normsq[n1]) + EPSF);
      const float mx = allmax(fmaxf(l0, l1));
      float q0 = expf(l0 - mx), q1 = expf(l1 - mx);
      const float inv = 1.f / allsum(q0 + q1);
      const float wg0 = g * q0 * inv + (1.f - g) * wprev[n0];
      const float wg1 = g * q1 * inv + (1.f - g) * wprev[n1];
      const float wgl = __shfl(wg1, (lane + 63) & 63);
      const float wgr = __shfl(wg0, (lane + 1) & 63);
      const float sh0 = s0 * wgl + s1 * wg0 + s2 * wg1;
      const float sh1 = s0 * wg0 + s1 * wg1 + s2 * wgr;
      const float wp0 = exp2f(gamma * log2f(sh0));
      const float wp1 = exp2f(gamma * log2f(sh1));
      const float itot = 1.f / (allsum(wp0 + wp1) + EPSF);
      wprev[n0] = wp0 * itot;
      wprev[n1] = wp1 * itot;
    }
    __syncthreads();  // b8
  }
}

extern "C" void kernel_launch(void* const* d_in, const int* in_sizes, int n_in,
                              void* d_out, int out_size, void* d_ws, size_t ws_size,
                              hipStream_t stream) {
  const float* x    = (const float*)d_in[0];
  const float* mem0 = (const float*)d_in[1];
  const float* wr0  = (const float*)d_in[2];
  const float* ww0  = (const float*)d_in[3];
  const float* h0   = (const float*)d_in[4];
  const float* Wx   = (const float*)d_in[5];
  const float* Wrd  = (const float*)d_in[6];
  const float* bh   = (const float*)d_in[7];
  const float* Wk   = (const float*)d_in[8];
  const float* bk   = (const float*)d_in[9];
  const float* Wb   = (const float*)d_in[10];
  const float* bb   = (const float*)d_in[11];
  const float* Wg   = (const float*)d_in[12];
  const float* bg   = (const float*)d_in[13];
  const float* Ws   = (const float*)d_in[14];
  const float* bs   = (const float*)d_in[15];
  const float* Wgam = (const float*)d_in[16];
  const float* bgam = (const float*)d_in[17];
  const float* We   = (const float*)d_in[18];
  const float* be   = (const float*)d_in[19];
  const float* Wa   = (const float*)d_in[20];
  const float* ba   = (const float*)d_in[21];
  float* out = (float*)d_out;
  unsigned int* wsb = (unsigned int*)d_ws;   // 65536 uints = 256 KB

  hipLaunchKernelGGL(ntm_prep, dim3(128), dim3(512), 0, stream, We, Wa, Wk, wsb);
  hipLaunchKernelGGL(ntm_kernel, dim3(128), dim3(NT), 0, stream,
                     x, mem0, wr0, ww0, h0, Wx, Wrd, bh, bk, Wb, bb,
                     Wg, bg, Ws, bs, Wgam, bgam, be, ba,
                     (const uint4*)wsb, out);
}

// Round 17
// 801.411 us; speedup vs baseline: 6.6910x; 1.0410x over previous
//
#include <hip/hip_runtime.h>
#include <math.h>

#define Tt 128
#define NT 512
#define EPSF 1e-8f

typedef _Float16 f16x2 __attribute__((ext_vector_type(2)));

__device__ __forceinline__ float fsigmoid(float v) { return 1.f / (1.f + expf(-v)); }
__device__ __forceinline__ float fsoftplus(float v) { return (v > 20.f) ? v : log1pf(expf(v)); }
__device__ __forceinline__ float ftanh(float v) { float e = expf(2.f * v); return 1.f - 2.f / (e + 1.f); }

__device__ __forceinline__ float dot2(f16x2 a, f16x2 b, float c) {
#if __has_builtin(__builtin_amdgcn_fdot2)
  return __builtin_amdgcn_fdot2(a, b, c, false);
#else
  return c + (float)a.x * (float)b.x + (float)a.y * (float)b.y;
#endif
}
__device__ __forceinline__ f16x2 pack2(float a, float b) {
  f16x2 p; p.x = (_Float16)a; p.y = (_Float16)b; return p;
}
__device__ __forceinline__ f16x2 bc16(unsigned int v) { return __builtin_bit_cast(f16x2, v); }

// ---- DPP reduction primitives ----
template <int C> __device__ __forceinline__ float dppadd(float v) {
  int s = __builtin_amdgcn_update_dpp(0, __builtin_bit_cast(int, v), C, 0xf, 0xf, true);
  return v + __builtin_bit_cast(float, s);
}
template <int C> __device__ __forceinline__ float dppmax(float v) {
  int iv = __builtin_bit_cast(int, v);
  int s = __builtin_amdgcn_update_dpp(iv, iv, C, 0xf, 0xf, false);
  return fmaxf(v, __builtin_bit_cast(float, s));
}
__device__ __forceinline__ float qsum16(float v) {
  v = dppadd<0x111>(v); v = dppadd<0x112>(v); v = dppadd<0x114>(v); v = dppadd<0x118>(v);
  return v;
}
__device__ __forceinline__ float halfsum(float v) {
  v = qsum16(v); v = dppadd<0x142>(v);
  return v;
}
__device__ __forceinline__ float allsum(float v) {
  v = halfsum(v); v = dppadd<0x143>(v);
  return __builtin_bit_cast(float, __builtin_amdgcn_readlane(__builtin_bit_cast(int, v), 63));
}
__device__ __forceinline__ float allmax(float v) {
  v = dppmax<0x111>(v); v = dppmax<0x112>(v); v = dppmax<0x114>(v);
  v = dppmax<0x118>(v); v = dppmax<0x142>(v); v = dppmax<0x143>(v);
  return __builtin_bit_cast(float, __builtin_amdgcn_readlane(__builtin_bit_cast(int, v), 63));
}

// ===== prep: pack big4 [We|Wa|Wk0|Wk1] f32 -> f16x2, column-owner layout =====
// uint idx i = (q*512 + col)*4 + e ; q=0..31 ; K elems (8q+2e, 8q+2e+1) of column col
// (col>>7 selects matrix, col&127 its column)
__global__ __launch_bounds__(512, 1) void ntm_prep(
    const float* __restrict__ We, const float* __restrict__ Wa,
    const float* __restrict__ Wk, unsigned int* __restrict__ wsb)
{
  const int i = blockIdx.x * 512 + threadIdx.x;   // grid 128*512 = 65536
  const int e = i & 3;
  const int col = (i >> 2) & 511;
  const int q = i >> 11;
  const int k0 = 8 * q + 2 * e;
  const int mat = col >> 7;
  const int mcol = col & 127;
  const float* base = (mat == 0) ? We : (mat == 1) ? Wa : (mat == 2) ? Wk : (Wk + 256 * 128);
  wsb[i] = __builtin_bit_cast(unsigned int,
             pack2(base[k0 * 128 + mcol], base[(k0 + 1) * 128 + mcol]));
}

__global__ __launch_bounds__(NT, 1) void ntm_kernel(
    const float* __restrict__ x, const float* __restrict__ mem0,
    const float* __restrict__ wr0, const float* __restrict__ ww0,
    const float* __restrict__ h0, const float* __restrict__ Wx,
    const float* __restrict__ Wrd, const float* __restrict__ bh,
    const float* __restrict__ bk,
    const float* __restrict__ Wb, const float* __restrict__ bb,
    const float* __restrict__ Wg, const float* __restrict__ bg,
    const float* __restrict__ Ws, const float* __restrict__ bs,
    const float* __restrict__ Wgam, const float* __restrict__ bgam,
    const float* __restrict__ be, const float* __restrict__ ba,
    const uint4* __restrict__ wsb4,
    float* __restrict__ out)
{
  const int b = blockIdx.x;
  const int t = threadIdx.x;
  const int lane = t & 63;
  const int wave = t >> 6;
  const int cg = t & 63;    // matmul column lane (P3)
  const int js = t >> 6;    // inner-dim slice (P3: 8 slices of 32)
  const int c4 = t & 31;    // float4 column group for mem passes
  const int rs = t >> 5;    // row slice for mem passes (16 slices)

  __shared__ __align__(16) float mem[128 * 128];   // 64 KB
  __shared__ __align__(16) uint4 lbigq[3584];      // 56 KB: big4 q-slices 25..31
  __shared__ __align__(16) float part[2048];       // 8 KB
  __shared__ __align__(16) float h_l[256];
  __shared__ __align__(16) unsigned int h16[128];  // h packed f16x2
  __shared__ __align__(16) float xf[128];
  __shared__ __align__(16) float rf[128];
  __shared__ __align__(16) float er[128];
  __shared__ __align__(16) float ad[128];
  __shared__ __align__(16) float kbuf[256];
  __shared__ float wsm_l[3072];
  __shared__ float wr_s[128], ww_s[128];
  __shared__ float normsq[128];
  __shared__ float dotv[256];
  __shared__ float scal[12];
  __shared__ float red2[4];
  __shared__ float bias_big[512];                  // [be | ba | bk0 | bk1]
  __shared__ float bh_l[256];
  __shared__ float bias_sm[12];

  // ===== C-matmul weights resident in regs: 64 f16x2
  f16x2 wcreg[64];
  {
    const float* basep = (js < 4) ? (Wx + (js * 32) * 256) : (Wrd + ((js - 4) * 32) * 256);
    #pragma unroll
    for (int c = 0; c < 4; ++c) {
      const float* bp = basep + c * 64 + cg;
      #pragma unroll
      for (int jj = 0; jj < 16; ++jj) {
        wcreg[c * 16 + jj] = pack2(bp[(2 * jj) * 256], bp[(2 * jj + 1) * 256]);
      }
    }
  }

  // ===== state / bias / small-weight / LDS-weight init =====
  for (int i = t; i < 128 * 128; i += NT) mem[i] = mem0[i];
  for (int i = t; i < 3584; i += NT) lbigq[i] = wsb4[12800 + i];  // q=25..31
  if (t < 128) { wr_s[t] = wr0[b * 128 + t]; ww_s[t] = ww0[b * 128 + t]; }
  if (t < 256) {
    float v = h0[b * 256 + t];
    h_l[t] = v; bh_l[t] = bh[t];
    const float vo = __shfl_xor(v, 1);
    if (!(t & 1)) h16[t >> 1] = __builtin_bit_cast(unsigned int, pack2(v, vo));
  }
  bias_big[t] = (t < 128) ? be[t] : (t < 256) ? ba[t - 128] : bk[t - 256];
  for (int i = t; i < 3072; i += NT) {
    const int d = i >> 8, j = i & 255;
    const int head = d / 6, kind = d % 6;
    float v;
    if (kind == 0)      v = Wb[head * 256 + j];
    else if (kind == 1) v = Wg[head * 256 + j];
    else if (kind == 2) v = Wgam[head * 256 + j];
    else                v = Ws[head * 768 + j * 3 + (kind - 3)];
    wsm_l[i] = v;
  }
  if (t < 12) {
    const int head = t / 6, kind = t % 6;
    bias_sm[t] = (kind == 0) ? bb[head] : (kind == 1) ? bg[head]
               : (kind == 2) ? bgam[head] : bs[head * 3 + (kind - 3)];
  }
  __syncthreads();

  const uint4* h16_4 = reinterpret_cast<const uint4*>(h16);

  // q=0..3 prefetch registers (issued early, consumed in P5)
  uint4 pf[4];
  auto issue_pf = [&]() {
    #pragma unroll
    for (int q = 0; q < 4; ++q) pf[q] = wsb4[q * 512 + t];
  };

  // ---- P5 fused: column-owner big4 (thread t = output col t) -> er/ad/kbuf
  //      + k^2 DPP + 12 small dots. No partials, no extra barrier.
  auto phase_big4 = [&]() {
    float a0 = 0.f, a1 = 0.f, a2 = 0.f, a3 = 0.f;
    #pragma unroll
    for (int q = 0; q < 32; ++q) {
      uint4 w;
      if (q < 4)        w = pf[q];
      else if (q >= 25) w = lbigq[(q - 25) * 512 + t];
      else              w = wsb4[q * 512 + t];
      const uint4 hq = h16_4[q];        // wave-uniform -> LDS broadcast
      a0 = dot2(bc16(hq.x), bc16(w.x), a0);
      a1 = dot2(bc16(hq.y), bc16(w.y), a1);
      a2 = dot2(bc16(hq.z), bc16(w.z), a2);
      a3 = dot2(bc16(hq.w), bc16(w.w), a3);
    }
    const float acc = (a0 + a1) + (a2 + a3) + bias_big[t];
    if (t < 128)      er[t] = fsigmoid(acc);
    else if (t < 256) ad[t - 128] = ftanh(acc);
    else {
      const float kv = ftanh(acc);
      kbuf[t - 256] = kv;
      float ks = kv * kv;
      ks = halfsum(ks); ks = dppadd<0x143>(ks);
      if (lane == 63) red2[wave - 4] = ks;
    }
    if (t < 384) {
      const int d = t >> 5, l5 = t & 31;
      float s = 0.f;
      #pragma unroll
      for (int q = 0; q < 8; ++q) s += h_l[l5 + 32 * q] * wsm_l[d * 256 + l5 + 32 * q];
      s = halfsum(s);
      if ((lane & 31) == 31) scal[d] = s + bias_sm[d];
    }
  };

  // prologue: er/ad/k/scal for step 0 from h0
  issue_pf();
  phase_big4();
  __syncthreads();

  for (int step = 0; step < Tt; ++step) {
    // ---- issue q=0..3 prefetch for this step's P5 (port works during P1-P4)
    issue_pf();

    // ---- P1: x_t -> xf; mem erase/add update; r partials
    if (t < 128) xf[t] = x[((size_t)b * Tt + step) * 128 + t];
    {
      const float4 e4 = *reinterpret_cast<const float4*>(&er[c4 * 4]);
      const float4 a4 = *reinterpret_cast<const float4*>(&ad[c4 * 4]);
      float rx = 0.f, ry = 0.f, rz = 0.f, rw = 0.f;
      #pragma unroll
      for (int k = 0; k < 8; ++k) {
        const int n = rs + 16 * k;
        const float wwn = ww_s[n], wrn = wr_s[n];
        float4 v = *reinterpret_cast<const float4*>(&mem[n * 128 + c4 * 4]);
        v.x = v.x * (1.f - wwn * e4.x) + wwn * a4.x;
        v.y = v.y * (1.f - wwn * e4.y) + wwn * a4.y;
        v.z = v.z * (1.f - wwn * e4.z) + wwn * a4.z;
        v.w = v.w * (1.f - wwn * e4.w) + wwn * a4.w;
        *reinterpret_cast<float4*>(&mem[n * 128 + c4 * 4]) = v;
        rx += wrn * v.x; ry += wrn * v.y; rz += wrn * v.z; rw += wrn * v.w;
      }
      // fold 16 slices into 2048 floats: slice rs -> part[(rs&15)*128 + col4]
      *reinterpret_cast<float4*>(&part[rs * 128 + c4 * 4]) = make_float4(rx, ry, rz, rw);
    }
    __syncthreads();  // b1

    // ---- P2: reduce r partials
    if (t < 128) {
      float r = 0.f;
      #pragma unroll
      for (int s = 0; s < 16; ++s) r += part[s * 128 + t];
      rf[t] = r;
    }
    __syncthreads();  // b2

    // ---- P3: C-matmul partials from [xf|rf] (reg-resident weights)
    {
      const float* src = (js < 4) ? (xf + js * 32) : (rf + (js - 4) * 32);
      float acc[4];
      #pragma unroll
      for (int c = 0; c < 4; ++c) acc[c] = 0.f;
      #pragma unroll
      for (int jj = 0; jj < 16; ++jj) {
        const float2 s2 = *reinterpret_cast<const float2*>(&src[2 * jj]);
        const f16x2 xx = pack2(s2.x, s2.y);
        #pragma unroll
        for (int c = 0; c < 4; ++c) acc[c] = dot2(xx, wcreg[c * 16 + jj], acc[c]);
      }
      #pragma unroll
      for (int c = 0; c < 4; ++c) part[js * 256 + c * 64 + cg] = acc[c];
    }
    __syncthreads();  // b3

    // ---- P4: h = tanh(.); write out; pack h16
    if (t < 256) {
      float v = bh_l[t];
      #pragma unroll
      for (int s = 0; s < 8; ++s) v += part[s * 256 + t];
      v = ftanh(v);
      h_l[t] = v;
      out[((size_t)b * Tt + step) * 256 + t] = v;
      const float vo = __shfl_xor(v, 1);
      if (!(t & 1)) h16[t >> 1] = __builtin_bit_cast(unsigned int, pack2(v, vo));
    }
    __syncthreads();  // b4

    // ---- P5: fused column-owner big4 + k^2 + small dots from new h
    phase_big4();
    __syncthreads();  // b5

    // ---- P7: content dots + row normsq fused (DPP half-reduction)
    {
      const int head = t >> 8;           // waves 0-3: head0, 4-7: head1
      const int u = t & 255;
      const int cc = u & 31, ns = u >> 5; // half-wave owns 16 rows
      const float4 k4 = *reinterpret_cast<const float4*>(&kbuf[head * 128 + cc * 4]);
      #pragma unroll
      for (int ch = 0; ch < 2; ++ch) {
        float dsum[8], qsum[8];
        #pragma unroll
        for (int ii = 0; ii < 8; ++ii) {
          const int n = ns * 16 + ch * 8 + ii;
          const float4 m4 = *reinterpret_cast<const float4*>(&mem[n * 128 + cc * 4]);
          dsum[ii] = k4.x * m4.x + k4.y * m4.y + k4.z * m4.z + k4.w * m4.w;
          qsum[ii] = m4.x * m4.x + m4.y * m4.y + m4.z * m4.z + m4.w * m4.w;
        }
        #pragma unroll
        for (int ii = 0; ii < 8; ++ii) dsum[ii] = halfsum(dsum[ii]);
        if (head == 0) {
          #pragma unroll
          for (int ii = 0; ii < 8; ++ii) qsum[ii] = halfsum(qsum[ii]);
        }
        if ((lane & 31) == 31) {
          #pragma unroll
          for (int ii = 0; ii < 8; ++ii) dotv[head * 128 + ns * 16 + ch * 8 + ii] = dsum[ii];
          if (head == 0) {
            #pragma unroll
            for (int ii = 0; ii < 8; ++ii) normsq[ns * 16 + ch * 8 + ii] = qsum[ii];
          }
        }
      }
    }
    __syncthreads();  // b6

    // ---- P8: addressing tail, wave0=head0, wave1=head1 (DPP all-reduces)
    if (wave < 2) {
      const int head = wave;
      const int h6 = head * 6;
      const float beta  = fsoftplus(scal[h6]);
      const float g     = fsigmoid(scal[h6 + 1]);
      const float gamma = 1.f + fsoftplus(scal[h6 + 2]);
      float e0 = scal[h6 + 3], e1 = scal[h6 + 4], e2 = scal[h6 + 5];
      const float mx3 = fmaxf(e0, fmaxf(e1, e2));
      float x0 = expf(e0 - mx3), x1 = expf(e1 - mx3), x2 = expf(e2 - mx3);
      const float si = 1.f / (x0 + x1 + x2);
      const float s0 = x0 * si, s1 = x1 * si, s2 = x2 * si;
      const float knorm = sqrtf(red2[2 * head] + red2[2 * head + 1]);
      float* wprev = head ? ww_s : wr_s;
      const int n0 = 2 * lane, n1 = 2 * lane + 1;
      float l0 = beta * dotv[head * 128 + n0] / (knorm * sqrtf(normsq[n0]) + EPSF);
      float l1 = beta * dotv[head * 128 + n1] / (knorm * sqrtf(normsq[n1]) + EPSF);
      const float mx = allmax(fmaxf(l0, l1));
      float q0 = expf(l0 - mx), q1 = expf(l1 - mx);
      const float inv = 1.f / allsum(q0 + q1);
      const float wg0 = g * q0 * inv + (1.f - g) * wprev[n0];
      const float wg1 = g * q1 * inv + (1.f - g) * wprev[n1];
      const float wgl = __shfl(wg1, (lane + 63) & 63);
      const float wgr = __shfl(wg0, (lane + 1) & 63);
      const float sh0 = s0 * wgl + s1 * wg0 + s2 * wg1;
      const float sh1 = s0 * wg0 + s1 * wg1 + s2 * wgr;
      const float wp0 = exp2f(gamma * log2f(sh0));
      const float wp1 = exp2f(gamma * log2f(sh1));
      const float itot = 1.f / (allsum(wp0 + wp1) + EPSF);
      wprev[n0] = wp0 * itot;
      wprev[n1] = wp1 * itot;
    }
    __syncthreads();  // b7
  }
}

extern "C" void kernel_launch(void* const* d_in, const int* in_sizes, int n_in,
                              void* d_out, int out_size, void* d_ws, size_t ws_size,
                              hipStream_t stream) {
  const float* x    = (const float*)d_in[0];
  const float* mem0 = (const float*)d_in[1];
  const float* wr0  = (const float*)d_in[2];
  const float* ww0  = (const float*)d_in[3];
  const float* h0   = (const float*)d_in[4];
  const float* Wx   = (const float*)d_in[5];
  const float* Wrd  = (const float*)d_in[6];
  const float* bh   = (const float*)d_in[7];
  const float* Wk   = (const float*)d_in[8];
  const float* bk   = (const float*)d_in[9];
  const float* Wb   = (const float*)d_in[10];
  const float* bb   = (const float*)d_in[11];
  const float* Wg   = (const float*)d_in[12];
  const float* bg   = (const float*)d_in[13];
  const float* Ws   = (const float*)d_in[14];
  const float* bs   = (const float*)d_in[15];
  const float* Wgam = (const float*)d_in[16];
  const float* bgam = (const float*)d_in[17];
  const float* We   = (const float*)d_in[18];
  const float* be   = (const float*)d_in[19];
  const float* Wa   = (const float*)d_in[20];
  const float* ba   = (const float*)d_in[21];
  float* out = (float*)d_out;
  unsigned int* wsb = (unsigned int*)d_ws;   // 65536 uints = 256 KB

  hipLaunchKernelGGL(ntm_prep, dim3(128), dim3(512), 0, stream, We, Wa, Wk, wsb);
  hipLaunchKernelGGL(ntm_kernel, dim3(128), dim3(NT), 0, stream,
                     x, mem0, wr0, ww0, h0, Wx, Wrd, bh, bk, Wb, bb,
                     Wg, bg, Ws, bs, Wgam, bgam, be, ba,
                     (const uint4*)wsb, out);
}